// Round 5
// baseline (163.449 us; speedup 1.0000x reference)
//
#include <hip/hip_runtime.h>
#include <math.h>

#define HH 96
#define WW 96
#define PP 9216   // H*W
#define CCH 256
#define BB 4
#define CH 32

typedef unsigned short u16;
typedef short bf16x8 __attribute__((ext_vector_type(8)));
typedef float f32x4 __attribute__((ext_vector_type(4)));

__device__ __forceinline__ float bf2f(unsigned s) { return __uint_as_float(s << 16); }
__device__ __forceinline__ u16 f2bf(float f) {
  unsigned u = __float_as_uint(f);
  return (u16)((u + 0x7fffu + ((u >> 16) & 1u)) >> 16);
}
__device__ __forceinline__ float4 unpack8(uint2 u) {
  return make_float4(bf2f(u.x & 0xffff), bf2f(u.x >> 16),
                     bf2f(u.y & 0xffff), bf2f(u.y >> 16));
}

typedef __attribute__((address_space(1))) const unsigned int GUI;
typedef __attribute__((address_space(3))) unsigned int LUI;
__device__ __forceinline__ void gload16(const void* g, void* l) {
  __builtin_amdgcn_global_load_lds((GUI*)g, (LUI*)l, 16, 0, 0);
}

// ---------------------------------------------------------------------------
// Weight convert: wq then wo -> bf16 at Wbf[0:65536], [65536:131072]
// ---------------------------------------------------------------------------
__global__ __launch_bounds__(256)
void wcvt(const float* __restrict__ wq, const float* __restrict__ wo,
          u16* __restrict__ Wbf) {
  int i = blockIdx.x * 256 + threadIdx.x;
  const float* s = (i < 16384) ? (wq + (size_t)i * 4) : (wo + (size_t)(i - 16384) * 4);
  float4 v = *(const float4*)s;
  uint2 u;
  u.x = (unsigned)f2bf(v.x) | ((unsigned)f2bf(v.y) << 16);
  u.y = (unsigned)f2bf(v.z) | ((unsigned)f2bf(v.w) << 16);
  *(uint2*)(Wbf + (size_t)i * 4) = u;
}

// ---------------------------------------------------------------------------
// Prepass: NCHW f32 -> channel-last bf16. Xcl[(which*4+b)][p][c]
// ---------------------------------------------------------------------------
__global__ __launch_bounds__(256)
void prepass(const float* __restrict__ q, const float* __restrict__ k,
             const float* __restrict__ v, u16* __restrict__ Xcl) {
  __shared__ float Tt[64][33];
  const int t = threadIdx.x;
  const int pblk = blockIdx.x * 64;
  const int c0 = blockIdx.y * 32;
  const int b = blockIdx.z & 3;
  const int which = blockIdx.z >> 2;
  const float* X = ((which == 0) ? q : (which == 1) ? k : v) + (size_t)b * CCH * PP;
  u16* Y = Xcl + (size_t)blockIdx.z * ((size_t)PP * CCH);

  {
    int p4 = t & 15, c = t >> 4;
#pragma unroll
    for (int i = 0; i < 2; i++) {
      int cc = c + 16 * i;
      float4 vv = *(const float4*)(X + (size_t)(c0 + cc) * PP + pblk + p4 * 4);
      Tt[p4 * 4 + 0][cc] = vv.x;
      Tt[p4 * 4 + 1][cc] = vv.y;
      Tt[p4 * 4 + 2][cc] = vv.z;
      Tt[p4 * 4 + 3][cc] = vv.w;
    }
  }
  __syncthreads();
  int p = t >> 2, cg = t & 3;
  unsigned wds[4];
#pragma unroll
  for (int j = 0; j < 4; j++) {
    u16 lo = f2bf(Tt[p][cg * 8 + 2 * j]);
    u16 hi = f2bf(Tt[p][cg * 8 + 2 * j + 1]);
    wds[j] = (unsigned)lo | ((unsigned)hi << 16);
  }
  uint4 st = {wds[0], wds[1], wds[2], wds[3]};
  *(uint4*)(Y + (size_t)(pblk + p) * CCH + c0 + cg * 8) = st;
}

// ---------------------------------------------------------------------------
// MFMA GEMM (unchanged from R4). MODE 0: proj, in-place bf16 CL. MODE 1: out.
// ---------------------------------------------------------------------------
template <int MODE>
__global__ __launch_bounds__(256)
void gemm_mfma(u16* __restrict__ XY, const u16* __restrict__ Wbf,
               const float* __restrict__ bias, float* __restrict__ outY) {
  __shared__ u16 Wl[256 * 64];   // 32 KB
  __shared__ u16 Xl[64 * 64];    // 8 KB
  const int t = threadIdx.x;
  const int w = t >> 6, l = t & 63;
  const int lr = l & 15, lg = l >> 4;
  const int pblk = blockIdx.x * 64;
  const int z = blockIdx.z;
  u16* Xbuf = XY + (size_t)z * ((size_t)PP * CCH);

  f32x4 acc[4][4];
#pragma unroll
  for (int mi = 0; mi < 4; mi++)
#pragma unroll
    for (int ni = 0; ni < 4; ni++) acc[mi][ni] = (f32x4){0.f, 0.f, 0.f, 0.f};

  for (int kk = 0; kk < 4; kk++) {
    const int c0 = kk * 64;
#pragma unroll
    for (int i = 0; i < 8; i++) {
      int r0 = (w * 8 + i) * 8;
      int row = r0 + (l >> 3);
      int gs = (l & 7) ^ (row & 7);
      gload16(Wbf + (size_t)row * CCH + c0 + gs * 8, (void*)&Wl[r0 * 64]);
    }
#pragma unroll
    for (int i = 0; i < 2; i++) {
      int r0 = (w * 2 + i) * 8;
      int row = r0 + (l >> 3);
      int gs = (l & 7) ^ (row & 7);
      gload16(Xbuf + (size_t)(pblk + row) * CCH + c0 + gs * 8, (void*)&Xl[r0 * 64]);
    }
    __syncthreads();
#pragma unroll
    for (int ks = 0; ks < 2; ks++) {
      const int g = ks * 4 + lg;
      bf16x8 wf[4], xf[4];
#pragma unroll
      for (int i = 0; i < 4; i++) {
        int row = w * 64 + i * 16 + lr;
        wf[i] = *(const bf16x8*)&Wl[row * 64 + ((g ^ (row & 7)) << 3)];
      }
#pragma unroll
      for (int i = 0; i < 4; i++) {
        int row = i * 16 + lr;
        xf[i] = *(const bf16x8*)&Xl[row * 64 + ((g ^ (row & 7)) << 3)];
      }
#pragma unroll
      for (int mi = 0; mi < 4; mi++)
#pragma unroll
        for (int ni = 0; ni < 4; ni++) {
          if (MODE == 0)
            acc[mi][ni] = __builtin_amdgcn_mfma_f32_16x16x32_bf16(
                wf[mi], xf[ni], acc[mi][ni], 0, 0, 0);
          else
            acc[mi][ni] = __builtin_amdgcn_mfma_f32_16x16x32_bf16(
                xf[mi], wf[ni], acc[mi][ni], 0, 0, 0);
        }
    }
    __syncthreads();
  }

  if (MODE == 0) {
#pragma unroll
    for (int mi = 0; mi < 4; mi++)
#pragma unroll
      for (int ni = 0; ni < 4; ni++) {
        int o = w * 64 + mi * 16 + lg * 4;
        int p = pblk + ni * 16 + lr;
        f32x4 a = acc[mi][ni];
        uint2 u;
        u.x = (unsigned)f2bf(a[0]) | ((unsigned)f2bf(a[1]) << 16);
        u.y = (unsigned)f2bf(a[2]) | ((unsigned)f2bf(a[3]) << 16);
        *(uint2*)(Xbuf + (size_t)p * CCH + o) = u;
      }
  } else {
#pragma unroll
    for (int ni = 0; ni < 4; ni++) {
      int o = w * 64 + ni * 16 + lr;
      float bv = bias[o];
#pragma unroll
      for (int mi = 0; mi < 4; mi++) {
        int p = pblk + mi * 16 + lg * 4;
        f32x4 a = acc[mi][ni];
        float4 st = {a[0] + bv, a[1] + bv, a[2] + bv, a[3] + bv};
        *(float4*)(outY + ((size_t)z * CCH + o) * PP + p) = st;
      }
    }
  }
}

// ---------------------------------------------------------------------------
// Attention, half-split: 2 lanes per (pixel, head), 16 ch each.
// Tile 32x4 pixels, halo 34x6, f32 LDS rows of 34 floats (136 B stride:
// start bank = 2*hp + 16*h2 + 4j mod 32 -> even spread, b128-minimal).
// Score dot completed via __shfl_xor(s, 32). __launch_bounds__(256,4) caps
// VGPR at 128 for 4 waves/SIMD.
// ---------------------------------------------------------------------------
#define TX 32
#define TY 4
#define HX 34
#define HY 6
#define NHP (HX * HY)    // 204 halo pixels
#define RS 34            // f32 row stride

__global__ __launch_bounds__(256, 4)
void attn_half(const u16* __restrict__ Kt, const u16* __restrict__ Vt,
               u16* __restrict__ Qt, const float* __restrict__ pe_dw,
               const float* __restrict__ pe_pw) {
  __shared__ float kvh[NHP * RS];   // 27,744 B
  __shared__ float coef[81];
  const int t = threadIdx.x;
  if (t < 81) coef[t] = pe_pw[t] * pe_dw[t % 9];

  const int lx = t & 31;
  const int h2 = (t >> 5) & 1;
  const int ly = t >> 6;
  const int x0 = blockIdx.x * TX;
  const int y0 = blockIdx.y * TY;
  const int b = blockIdx.z >> 3;
  const int h = blockIdx.z & 7;
  const size_t nbase = (size_t)b * PP * CCH + h * CH;
  const int p = (y0 + ly) * WW + (x0 + lx);
  const size_t pixhalf = nbase + (size_t)p * CCH + h2 * 16;

  // q half (16 ch)
  float qh[16];
  {
    uint4 u0 = *(const uint4*)(Qt + pixhalf);
    uint4 u1 = *(const uint4*)(Qt + pixhalf + 8);
    float4 a = unpack8(make_uint2(u0.x, u0.y));
    float4 c = unpack8(make_uint2(u0.z, u0.w));
    float4 d = unpack8(make_uint2(u1.x, u1.y));
    float4 e = unpack8(make_uint2(u1.z, u1.w));
    qh[0] = a.x; qh[1] = a.y; qh[2] = a.z; qh[3] = a.w;
    qh[4] = c.x; qh[5] = c.y; qh[6] = c.z; qh[7] = c.w;
    qh[8] = d.x; qh[9] = d.y; qh[10] = d.z; qh[11] = d.w;
    qh[12] = e.x; qh[13] = e.y; qh[14] = e.z; qh[15] = e.w;
  }

  // ---- stage K halo (bf16 global -> f32 LDS, zero-fill OOB) ----
  for (int s = t; s < NHP * 8; s += 256) {
    int pix = s >> 3, j = s & 7;
    int hy = pix / HX, hx = pix - hy * HX;
    int gx = x0 - 1 + hx, gy = y0 - 1 + hy;
    uint2 u = make_uint2(0u, 0u);
    if (gx >= 0 && gx < WW && gy >= 0 && gy < HH)
      u = *(const uint2*)(Kt + nbase + (size_t)(gy * WW + gx) * CCH + j * 4);
    *(float4*)(&kvh[pix * RS + j * 4]) = unpack8(u);
  }
  __syncthreads();

  // ---- scores: half-dot + cross-half shuffle ----
  float f[9];
#pragma unroll
  for (int kk = 0; kk < 9; kk++) {
    int hx = lx + kk % 3, hy = ly + kk / 3;
    const float* kp = &kvh[(hy * HX + hx) * RS + h2 * 16];
    float s = 0.f;
#pragma unroll
    for (int j = 0; j < 4; j++) {
      float4 kv4 = *(const float4*)(kp + j * 4);
      s = fmaf(qh[4 * j + 0], kv4.x, s);
      s = fmaf(qh[4 * j + 1], kv4.y, s);
      s = fmaf(qh[4 * j + 2], kv4.z, s);
      s = fmaf(qh[4 * j + 3], kv4.w, s);
    }
    f[kk] = s + __shfl_xor(s, 32, 64);
  }

  // ---- PE mix + softmax over 9 (duplicated in both halves) ----
  float g[9], m = -1e30f;
#pragma unroll
  for (int k2 = 0; k2 < 9; k2++) {
    float s = 0.f;
#pragma unroll
    for (int kk = 0; kk < 9; kk++) s = fmaf(coef[k2 * 9 + kk], f[kk], s);
    g[k2] = s;
    m = fmaxf(m, s);
  }
  float ssum = 0.f;
#pragma unroll
  for (int k2 = 0; k2 < 9; k2++) {
    g[k2] = __expf(g[k2] - m);
    ssum += g[k2];
  }
  float inv = 1.f / ssum;
#pragma unroll
  for (int k2 = 0; k2 < 9; k2++) g[k2] *= inv;

  // ---- stage V halo ----
  __syncthreads();
  for (int s = t; s < NHP * 8; s += 256) {
    int pix = s >> 3, j = s & 7;
    int hy = pix / HX, hx = pix - hy * HX;
    int gx = x0 - 1 + hx, gy = y0 - 1 + hy;
    uint2 u = make_uint2(0u, 0u);
    if (gx >= 0 && gx < WW && gy >= 0 && gy < HH)
      u = *(const uint2*)(Vt + nbase + (size_t)(gy * WW + gx) * CCH + j * 4);
    *(float4*)(&kvh[pix * RS + j * 4]) = unpack8(u);
  }
  __syncthreads();

  // ---- O half = sum_k g[k] * V_half[neighbor k] ----
  float oh[16];
#pragma unroll
  for (int j = 0; j < 16; j++) oh[j] = 0.f;
#pragma unroll
  for (int kk = 0; kk < 9; kk++) {
    int hx = lx + kk % 3, hy = ly + kk / 3;
    const float* vp = &kvh[(hy * HX + hx) * RS + h2 * 16];
    float gv = g[kk];
#pragma unroll
    for (int j = 0; j < 4; j++) {
      float4 vv = *(const float4*)(vp + j * 4);
      oh[4 * j + 0] = fmaf(gv, vv.x, oh[4 * j + 0]);
      oh[4 * j + 1] = fmaf(gv, vv.y, oh[4 * j + 1]);
      oh[4 * j + 2] = fmaf(gv, vv.z, oh[4 * j + 2]);
      oh[4 * j + 3] = fmaf(gv, vv.w, oh[4 * j + 3]);
    }
  }
  uint4 s0, s1;
  s0.x = (unsigned)f2bf(oh[0]) | ((unsigned)f2bf(oh[1]) << 16);
  s0.y = (unsigned)f2bf(oh[2]) | ((unsigned)f2bf(oh[3]) << 16);
  s0.z = (unsigned)f2bf(oh[4]) | ((unsigned)f2bf(oh[5]) << 16);
  s0.w = (unsigned)f2bf(oh[6]) | ((unsigned)f2bf(oh[7]) << 16);
  s1.x = (unsigned)f2bf(oh[8]) | ((unsigned)f2bf(oh[9]) << 16);
  s1.y = (unsigned)f2bf(oh[10]) | ((unsigned)f2bf(oh[11]) << 16);
  s1.z = (unsigned)f2bf(oh[12]) | ((unsigned)f2bf(oh[13]) << 16);
  s1.w = (unsigned)f2bf(oh[14]) | ((unsigned)f2bf(oh[15]) << 16);
  *(uint4*)(Qt + pixhalf) = s0;
  *(uint4*)(Qt + pixhalf + 8) = s1;
}

// ---------------------------------------------------------------------------
extern "C" void kernel_launch(void* const* d_in, const int* in_sizes, int n_in,
                              void* d_out, int out_size, void* d_ws, size_t ws_size,
                              hipStream_t stream) {
  const float* q     = (const float*)d_in[0];
  const float* k     = (const float*)d_in[1];
  const float* v     = (const float*)d_in[2];
  const float* wq    = (const float*)d_in[3];
  const float* pe_dw = (const float*)d_in[4];
  const float* pe_pw = (const float*)d_in[5];
  const float* wo    = (const float*)d_in[6];
  const float* bo    = (const float*)d_in[7];
  float* out = (float*)d_out;

  const size_t seg = (size_t)BB * PP * CCH;      // elements per [B,P,C] tensor
  u16* Xcl = (u16*)d_ws;                         // 3*seg bf16: q,k,v (in-place proj)
  u16* Wbf = Xcl + 3 * seg;                      // 131072 bf16: wq | wo

  wcvt<<<128, 256, 0, stream>>>(wq, wo, Wbf);
  prepass<<<dim3(PP / 64, CCH / 32, 12), 256, 0, stream>>>(q, k, v, Xcl);

  gemm_mfma<0><<<dim3(PP / 64, 1, 12), 256, 0, stream>>>(Xcl, Wbf, nullptr, nullptr);

  u16* Qs = Xcl;
  u16* Ks = Xcl + seg;
  u16* Vs = Xcl + 2 * seg;
  attn_half<<<dim3(WW / TX, HH / TY, BB * 8), 256, 0, stream>>>(Ks, Vs, Qs, pe_dw, pe_pw);

  gemm_mfma<1><<<dim3(PP / 64, 1, BB), 256, 0, stream>>>(Qs, Wbf + 65536, bo, out);
}

// Round 6
// 160.231 us; speedup vs baseline: 1.0201x; 1.0201x over previous
//
#include <hip/hip_runtime.h>
#include <math.h>

#define HH 96
#define WW 96
#define PP 9216   // H*W
#define CCH 256
#define BB 4
#define CH 32

typedef unsigned short u16;
typedef short bf16x8 __attribute__((ext_vector_type(8)));
typedef float f32x4 __attribute__((ext_vector_type(4)));

__device__ __forceinline__ float bf2f(unsigned s) { return __uint_as_float(s << 16); }
__device__ __forceinline__ u16 f2bf(float f) {
  unsigned u = __float_as_uint(f);
  return (u16)((u + 0x7fffu + ((u >> 16) & 1u)) >> 16);
}
__device__ __forceinline__ float4 unpack8(uint2 u) {
  return make_float4(bf2f(u.x & 0xffff), bf2f(u.x >> 16),
                     bf2f(u.y & 0xffff), bf2f(u.y >> 16));
}

typedef __attribute__((address_space(1))) const unsigned int GUI;
typedef __attribute__((address_space(3))) unsigned int LUI;
__device__ __forceinline__ void gload16(const void* g, void* l) {
  __builtin_amdgcn_global_load_lds((GUI*)g, (LUI*)l, 16, 0, 0);
}

// ---------------------------------------------------------------------------
// Weight convert: wq then wo -> bf16 at Wbf[0:65536], [65536:131072]
// ---------------------------------------------------------------------------
__global__ __launch_bounds__(256)
void wcvt(const float* __restrict__ wq, const float* __restrict__ wo,
          u16* __restrict__ Wbf) {
  int i = blockIdx.x * 256 + threadIdx.x;
  const float* s = (i < 16384) ? (wq + (size_t)i * 4) : (wo + (size_t)(i - 16384) * 4);
  float4 v = *(const float4*)s;
  uint2 u;
  u.x = (unsigned)f2bf(v.x) | ((unsigned)f2bf(v.y) << 16);
  u.y = (unsigned)f2bf(v.z) | ((unsigned)f2bf(v.w) << 16);
  *(uint2*)(Wbf + (size_t)i * 4) = u;
}

// ---------------------------------------------------------------------------
// Prepass: NCHW f32 -> channel-last bf16. Xcl[(which*4+b)][p][c]
// ---------------------------------------------------------------------------
__global__ __launch_bounds__(256)
void prepass(const float* __restrict__ q, const float* __restrict__ k,
             const float* __restrict__ v, u16* __restrict__ Xcl) {
  __shared__ float Tt[64][33];
  const int t = threadIdx.x;
  const int pblk = blockIdx.x * 64;
  const int c0 = blockIdx.y * 32;
  const int b = blockIdx.z & 3;
  const int which = blockIdx.z >> 2;
  const float* X = ((which == 0) ? q : (which == 1) ? k : v) + (size_t)b * CCH * PP;
  u16* Y = Xcl + (size_t)blockIdx.z * ((size_t)PP * CCH);

  {
    int p4 = t & 15, c = t >> 4;
#pragma unroll
    for (int i = 0; i < 2; i++) {
      int cc = c + 16 * i;
      float4 vv = *(const float4*)(X + (size_t)(c0 + cc) * PP + pblk + p4 * 4);
      Tt[p4 * 4 + 0][cc] = vv.x;
      Tt[p4 * 4 + 1][cc] = vv.y;
      Tt[p4 * 4 + 2][cc] = vv.z;
      Tt[p4 * 4 + 3][cc] = vv.w;
    }
  }
  __syncthreads();
  int p = t >> 2, cg = t & 3;
  unsigned wds[4];
#pragma unroll
  for (int j = 0; j < 4; j++) {
    u16 lo = f2bf(Tt[p][cg * 8 + 2 * j]);
    u16 hi = f2bf(Tt[p][cg * 8 + 2 * j + 1]);
    wds[j] = (unsigned)lo | ((unsigned)hi << 16);
  }
  uint4 st = {wds[0], wds[1], wds[2], wds[3]};
  *(uint4*)(Y + (size_t)(pblk + p) * CCH + c0 + cg * 8) = st;
}

// ---------------------------------------------------------------------------
// MFMA GEMM (unchanged). MODE 0: proj, in-place bf16 CL. MODE 1: out proj.
// ---------------------------------------------------------------------------
template <int MODE>
__global__ __launch_bounds__(256)
void gemm_mfma(u16* __restrict__ XY, const u16* __restrict__ Wbf,
               const float* __restrict__ bias, float* __restrict__ outY) {
  __shared__ u16 Wl[256 * 64];   // 32 KB
  __shared__ u16 Xl[64 * 64];    // 8 KB
  const int t = threadIdx.x;
  const int w = t >> 6, l = t & 63;
  const int lr = l & 15, lg = l >> 4;
  const int pblk = blockIdx.x * 64;
  const int z = blockIdx.z;
  u16* Xbuf = XY + (size_t)z * ((size_t)PP * CCH);

  f32x4 acc[4][4];
#pragma unroll
  for (int mi = 0; mi < 4; mi++)
#pragma unroll
    for (int ni = 0; ni < 4; ni++) acc[mi][ni] = (f32x4){0.f, 0.f, 0.f, 0.f};

  for (int kk = 0; kk < 4; kk++) {
    const int c0 = kk * 64;
#pragma unroll
    for (int i = 0; i < 8; i++) {
      int r0 = (w * 8 + i) * 8;
      int row = r0 + (l >> 3);
      int gs = (l & 7) ^ (row & 7);
      gload16(Wbf + (size_t)row * CCH + c0 + gs * 8, (void*)&Wl[r0 * 64]);
    }
#pragma unroll
    for (int i = 0; i < 2; i++) {
      int r0 = (w * 2 + i) * 8;
      int row = r0 + (l >> 3);
      int gs = (l & 7) ^ (row & 7);
      gload16(Xbuf + (size_t)(pblk + row) * CCH + c0 + gs * 8, (void*)&Xl[r0 * 64]);
    }
    __syncthreads();
#pragma unroll
    for (int ks = 0; ks < 2; ks++) {
      const int g = ks * 4 + lg;
      bf16x8 wf[4], xf[4];
#pragma unroll
      for (int i = 0; i < 4; i++) {
        int row = w * 64 + i * 16 + lr;
        wf[i] = *(const bf16x8*)&Wl[row * 64 + ((g ^ (row & 7)) << 3)];
      }
#pragma unroll
      for (int i = 0; i < 4; i++) {
        int row = i * 16 + lr;
        xf[i] = *(const bf16x8*)&Xl[row * 64 + ((g ^ (row & 7)) << 3)];
      }
#pragma unroll
      for (int mi = 0; mi < 4; mi++)
#pragma unroll
        for (int ni = 0; ni < 4; ni++) {
          if (MODE == 0)
            acc[mi][ni] = __builtin_amdgcn_mfma_f32_16x16x32_bf16(
                wf[mi], xf[ni], acc[mi][ni], 0, 0, 0);
          else
            acc[mi][ni] = __builtin_amdgcn_mfma_f32_16x16x32_bf16(
                xf[mi], wf[ni], acc[mi][ni], 0, 0, 0);
        }
    }
    __syncthreads();
  }

  if (MODE == 0) {
#pragma unroll
    for (int mi = 0; mi < 4; mi++)
#pragma unroll
      for (int ni = 0; ni < 4; ni++) {
        int o = w * 64 + mi * 16 + lg * 4;
        int p = pblk + ni * 16 + lr;
        f32x4 a = acc[mi][ni];
        uint2 u;
        u.x = (unsigned)f2bf(a[0]) | ((unsigned)f2bf(a[1]) << 16);
        u.y = (unsigned)f2bf(a[2]) | ((unsigned)f2bf(a[3]) << 16);
        *(uint2*)(Xbuf + (size_t)p * CCH + o) = u;
      }
  } else {
#pragma unroll
    for (int ni = 0; ni < 4; ni++) {
      int o = w * 64 + ni * 16 + lr;
      float bv = bias[o];
#pragma unroll
      for (int mi = 0; mi < 4; mi++) {
        int p = pblk + mi * 16 + lg * 4;
        f32x4 a = acc[mi][ni];
        float4 st = {a[0] + bv, a[1] + bv, a[2] + bv, a[3] + bv};
        *(float4*)(outY + ((size_t)z * CCH + o) * PP + p) = st;
      }
    }
  }
}

// ---------------------------------------------------------------------------
// Attention, half-split (2 lanes per pixel-head, 16 ch each), tile 32x4,
// halo 34x6, f32 LDS rows of RS=34 floats (conflict-free, measured R5).
// THIS ROUND: staging is fixed-trip fully-unrolled; all K AND V global loads
// issued up front into registers (deep MLP, one latency instead of 14 serial);
// V LDS-write deferred past scores/softmax (T14 async-STAGE split).
// ---------------------------------------------------------------------------
#define TX 32
#define TY 4
#define HX 34
#define HY 6
#define NHP (HX * HY)    // 204 halo pixels
#define NSL (NHP * 8)    // 1632 uint2 slots
#define NRND 7           // ceil(1632/256)
#define RS 34            // f32 row stride

__global__ __launch_bounds__(256, 4)
void attn_half(const u16* __restrict__ Kt, const u16* __restrict__ Vt,
               u16* __restrict__ Qt, const float* __restrict__ pe_dw,
               const float* __restrict__ pe_pw) {
  __shared__ float kvh[NHP * RS];   // 27,744 B
  __shared__ float coef[81];
  const int t = threadIdx.x;
  if (t < 81) coef[t] = pe_pw[t] * pe_dw[t % 9];

  const int lx = t & 31;
  const int h2 = (t >> 5) & 1;
  const int ly = t >> 6;
  const int x0 = blockIdx.x * TX;
  const int y0 = blockIdx.y * TY;
  const int b = blockIdx.z >> 3;
  const int h = blockIdx.z & 7;
  const size_t nbase = (size_t)b * PP * CCH + h * CH;
  const int p = (y0 + ly) * WW + (x0 + lx);
  const size_t pixhalf = nbase + (size_t)p * CCH + h2 * 16;

  // ---- issue ALL staged loads up front: K rounds, then V rounds ----
  uint2 kreg[NRND], vreg[NRND];
#pragma unroll
  for (int r = 0; r < NRND; r++) {
    int s = t + r * 256;
    int pix = s >> 3, j = s & 7;
    int hy = pix / HX, hx = pix - hy * HX;
    int gx = x0 - 1 + hx, gy = y0 - 1 + hy;
    bool ok = (s < NSL) & (gx >= 0) & (gx < WW) & (gy >= 0) & (gy < HH);
    uint2 u = make_uint2(0u, 0u);
    if (ok) u = *(const uint2*)(Kt + nbase + (size_t)(gy * WW + gx) * CCH + j * 4);
    kreg[r] = u;
  }
#pragma unroll
  for (int r = 0; r < NRND; r++) {
    int s = t + r * 256;
    int pix = s >> 3, j = s & 7;
    int hy = pix / HX, hx = pix - hy * HX;
    int gx = x0 - 1 + hx, gy = y0 - 1 + hy;
    bool ok = (s < NSL) & (gx >= 0) & (gx < WW) & (gy >= 0) & (gy < HH);
    uint2 u = make_uint2(0u, 0u);
    if (ok) u = *(const uint2*)(Vt + nbase + (size_t)(gy * WW + gx) * CCH + j * 4);
    vreg[r] = u;
  }

  // q half (16 ch)
  float qh[16];
  {
    uint4 u0 = *(const uint4*)(Qt + pixhalf);
    uint4 u1 = *(const uint4*)(Qt + pixhalf + 8);
    float4 a = unpack8(make_uint2(u0.x, u0.y));
    float4 c = unpack8(make_uint2(u0.z, u0.w));
    float4 d = unpack8(make_uint2(u1.x, u1.y));
    float4 e = unpack8(make_uint2(u1.z, u1.w));
    qh[0] = a.x; qh[1] = a.y; qh[2] = a.z; qh[3] = a.w;
    qh[4] = c.x; qh[5] = c.y; qh[6] = c.z; qh[7] = c.w;
    qh[8] = d.x; qh[9] = d.y; qh[10] = d.z; qh[11] = d.w;
    qh[12] = e.x; qh[13] = e.y; qh[14] = e.z; qh[15] = e.w;
  }

  // ---- write K halo to LDS (waits K loads only; V stays in flight) ----
#pragma unroll
  for (int r = 0; r < NRND; r++) {
    int s = t + r * 256;
    if (s < NSL) {
      int pix = s >> 3, j = s & 7;
      *(float4*)(&kvh[pix * RS + j * 4]) = unpack8(kreg[r]);
    }
  }
  __syncthreads();

  // ---- scores: half-dot + cross-half shuffle ----
  float f[9];
#pragma unroll
  for (int kk = 0; kk < 9; kk++) {
    int hx = lx + kk % 3, hy = ly + kk / 3;
    const float* kp = &kvh[(hy * HX + hx) * RS + h2 * 16];
    float s = 0.f;
#pragma unroll
    for (int j = 0; j < 4; j++) {
      float4 kv4 = *(const float4*)(kp + j * 4);
      s = fmaf(qh[4 * j + 0], kv4.x, s);
      s = fmaf(qh[4 * j + 1], kv4.y, s);
      s = fmaf(qh[4 * j + 2], kv4.z, s);
      s = fmaf(qh[4 * j + 3], kv4.w, s);
    }
    f[kk] = s + __shfl_xor(s, 32, 64);
  }

  // ---- PE mix + softmax over 9 (duplicated in both halves) ----
  float g[9], m = -1e30f;
#pragma unroll
  for (int k2 = 0; k2 < 9; k2++) {
    float s = 0.f;
#pragma unroll
    for (int kk = 0; kk < 9; kk++) s = fmaf(coef[k2 * 9 + kk], f[kk], s);
    g[k2] = s;
    m = fmaxf(m, s);
  }
  float ssum = 0.f;
#pragma unroll
  for (int k2 = 0; k2 < 9; k2++) {
    g[k2] = __expf(g[k2] - m);
    ssum += g[k2];
  }
  float inv = 1.f / ssum;
#pragma unroll
  for (int k2 = 0; k2 < 9; k2++) g[k2] *= inv;

  // ---- write V halo (loads arrived long ago; latency hid under scores) ----
  __syncthreads();
#pragma unroll
  for (int r = 0; r < NRND; r++) {
    int s = t + r * 256;
    if (s < NSL) {
      int pix = s >> 3, j = s & 7;
      *(float4*)(&kvh[pix * RS + j * 4]) = unpack8(vreg[r]);
    }
  }
  __syncthreads();

  // ---- O half = sum_k g[k] * V_half[neighbor k] ----
  float oh[16];
#pragma unroll
  for (int j = 0; j < 16; j++) oh[j] = 0.f;
#pragma unroll
  for (int kk = 0; kk < 9; kk++) {
    int hx = lx + kk % 3, hy = ly + kk / 3;
    const float* vp = &kvh[(hy * HX + hx) * RS + h2 * 16];
    float gv = g[kk];
#pragma unroll
    for (int j = 0; j < 4; j++) {
      float4 vv = *(const float4*)(vp + j * 4);
      oh[4 * j + 0] = fmaf(gv, vv.x, oh[4 * j + 0]);
      oh[4 * j + 1] = fmaf(gv, vv.y, oh[4 * j + 1]);
      oh[4 * j + 2] = fmaf(gv, vv.z, oh[4 * j + 2]);
      oh[4 * j + 3] = fmaf(gv, vv.w, oh[4 * j + 3]);
    }
  }
  uint4 s0, s1;
  s0.x = (unsigned)f2bf(oh[0]) | ((unsigned)f2bf(oh[1]) << 16);
  s0.y = (unsigned)f2bf(oh[2]) | ((unsigned)f2bf(oh[3]) << 16);
  s0.z = (unsigned)f2bf(oh[4]) | ((unsigned)f2bf(oh[5]) << 16);
  s0.w = (unsigned)f2bf(oh[6]) | ((unsigned)f2bf(oh[7]) << 16);
  s1.x = (unsigned)f2bf(oh[8]) | ((unsigned)f2bf(oh[9]) << 16);
  s1.y = (unsigned)f2bf(oh[10]) | ((unsigned)f2bf(oh[11]) << 16);
  s1.z = (unsigned)f2bf(oh[12]) | ((unsigned)f2bf(oh[13]) << 16);
  s1.w = (unsigned)f2bf(oh[14]) | ((unsigned)f2bf(oh[15]) << 16);
  *(uint4*)(Qt + pixhalf) = s0;
  *(uint4*)(Qt + pixhalf + 8) = s1;
}

// ---------------------------------------------------------------------------
extern "C" void kernel_launch(void* const* d_in, const int* in_sizes, int n_in,
                              void* d_out, int out_size, void* d_ws, size_t ws_size,
                              hipStream_t stream) {
  const float* q     = (const float*)d_in[0];
  const float* k     = (const float*)d_in[1];
  const float* v     = (const float*)d_in[2];
  const float* wq    = (const float*)d_in[3];
  const float* pe_dw = (const float*)d_in[4];
  const float* pe_pw = (const float*)d_in[5];
  const float* wo    = (const float*)d_in[6];
  const float* bo    = (const float*)d_in[7];
  float* out = (float*)d_out;

  const size_t seg = (size_t)BB * PP * CCH;      // elements per [B,P,C] tensor
  u16* Xcl = (u16*)d_ws;                         // 3*seg bf16: q,k,v (in-place proj)
  u16* Wbf = Xcl + 3 * seg;                      // 131072 bf16: wq | wo

  wcvt<<<128, 256, 0, stream>>>(wq, wo, Wbf);
  prepass<<<dim3(PP / 64, CCH / 32, 12), 256, 0, stream>>>(q, k, v, Xcl);

  gemm_mfma<0><<<dim3(PP / 64, 1, 12), 256, 0, stream>>>(Xcl, Wbf, nullptr, nullptr);

  u16* Qs = Xcl;
  u16* Ks = Xcl + seg;
  u16* Vs = Xcl + 2 * seg;
  attn_half<<<dim3(WW / TX, HH / TY, BB * 8), 256, 0, stream>>>(Ks, Vs, Qs, pe_dw, pe_pw);

  gemm_mfma<1><<<dim3(PP / 64, 1, BB), 256, 0, stream>>>(Qs, Wbf + 65536, bo, out);
}

// Round 7
// 95.401 us; speedup vs baseline: 1.7133x; 1.6796x over previous
//
#include <hip/hip_runtime.h>
#include <math.h>

#define HH 96
#define WW 96
#define PP 9216   // H*W
#define CCH 256
#define BB 4
#define CH 32

typedef unsigned short u16;
typedef short bf16x8 __attribute__((ext_vector_type(8)));
typedef float f32x4 __attribute__((ext_vector_type(4)));

__device__ __forceinline__ float bf2f(unsigned s) { return __uint_as_float(s << 16); }
__device__ __forceinline__ u16 f2bf(float f) {
  unsigned u = __float_as_uint(f);
  return (u16)((u + 0x7fffu + ((u >> 16) & 1u)) >> 16);
}

typedef __attribute__((address_space(1))) const unsigned int GUI;
typedef __attribute__((address_space(3))) unsigned int LUI;
__device__ __forceinline__ void gload16(const void* g, void* l) {
  __builtin_amdgcn_global_load_lds((GUI*)g, (LUI*)l, 16, 0, 0);
}

// ---------------------------------------------------------------------------
// Weight convert: wq then wo -> bf16 at Wbf[0:65536], [65536:131072]
// ---------------------------------------------------------------------------
__global__ __launch_bounds__(256)
void wcvt(const float* __restrict__ wq, const float* __restrict__ wo,
          u16* __restrict__ Wbf) {
  int i = blockIdx.x * 256 + threadIdx.x;
  const float* s = (i < 16384) ? (wq + (size_t)i * 4) : (wo + (size_t)(i - 16384) * 4);
  float4 v = *(const float4*)s;
  uint2 u;
  u.x = (unsigned)f2bf(v.x) | ((unsigned)f2bf(v.y) << 16);
  u.y = (unsigned)f2bf(v.z) | ((unsigned)f2bf(v.w) << 16);
  *(uint2*)(Wbf + (size_t)i * 4) = u;
}

// ---------------------------------------------------------------------------
// Fused projection GEMM: reads f32 NCHW (q/k/v by z), converts+transposes
// in-kernel (static 4x4 cross-lane shfl transpose), MFMA, writes bf16 CL.
// Y[p][o] tile: o full 256 (wave w owns o=w*64..), p-tile 64, BK=64.
// ---------------------------------------------------------------------------
__global__ __launch_bounds__(256)
void gemm_qkvf(const float* __restrict__ qin, const float* __restrict__ kin,
               const float* __restrict__ vin, const u16* __restrict__ Wbf,
               u16* __restrict__ Xcl) {
  __shared__ u16 Wl[256 * 64];   // 32 KB
  __shared__ u16 Xl[64 * 64];    // 8 KB
  const int t = threadIdx.x;
  const int w = t >> 6, l = t & 63;
  const int lr = l & 15, lg = l >> 4;
  const int pblk = blockIdx.x * 64;
  const int z = blockIdx.z;
  const int b = z & 3, which = z >> 2;
  const float* Xf = ((which == 0) ? qin : (which == 1) ? kin : vin) + (size_t)b * CCH * PP;
  u16* Y = Xcl + (size_t)z * ((size_t)PP * CCH);

  f32x4 acc[4][4];
#pragma unroll
  for (int mi = 0; mi < 4; mi++)
#pragma unroll
    for (int ni = 0; ni < 4; ni++) acc[mi][ni] = (f32x4){0.f, 0.f, 0.f, 0.f};

  for (int kk = 0; kk < 4; kk++) {
    const int c0 = kk * 64;
    // stage W tile: 256 rows x 64c via global_load_lds (source pre-swizzled)
#pragma unroll
    for (int i = 0; i < 8; i++) {
      int r0 = (w * 8 + i) * 8;
      int row = r0 + (l >> 3);
      int gs = (l & 7) ^ (row & 7);
      gload16(Wbf + (size_t)row * CCH + c0 + gs * 8, (void*)&Wl[r0 * 64]);
    }
    // load X f32 NCHW: 4 rounds, coalesced along p
    float4 xr[4];
#pragma unroll
    for (int rr = 0; rr < 4; rr++) {
      int cc = w * 4 + rr * 16 + lg;
      xr[rr] = *(const float4*)(Xf + (size_t)(c0 + cc) * PP + pblk + lr * 4);
    }
    // static 4x4 cross-lane transpose (g-bits <-> p-quad bits), cvt, LDS write
#pragma unroll
    for (int rr = 0; rr < 4; rr++) {
      float r0 = xr[rr].x, r1 = xr[rr].y, r2 = xr[rr].z, r3 = xr[rr].w;
      bool b0 = (lg & 1), b1 = (lg & 2);
      float s0 = b0 ? r0 : r1;
      float s1 = b0 ? r2 : r3;
      float u0 = __shfl_xor(s0, 16, 64);
      float u1 = __shfl_xor(s1, 16, 64);
      float m0 = b0 ? u0 : r0;
      float m1 = b0 ? r1 : u0;
      float m2 = b0 ? u1 : r2;
      float m3 = b0 ? r3 : u1;
      float s2 = b1 ? m0 : m2;
      float s3 = b1 ? m1 : m3;
      float w0 = __shfl_xor(s2, 32, 64);
      float w1 = __shfl_xor(s3, 32, 64);
      float o0 = b1 ? w0 : m0;
      float o1 = b1 ? w1 : m1;
      float o2 = b1 ? m2 : w0;
      float o3 = b1 ? m3 : w1;
      // lane now holds c = cbase..cbase+3 of p-row pl
      int cbase = w * 4 + rr * 16;
      int pl = lr * 4 + lg;
      int qg = cbase >> 3, h8 = (cbase >> 2) & 1;
      unsigned lo = (unsigned)f2bf(o0) | ((unsigned)f2bf(o1) << 16);
      unsigned hi = (unsigned)f2bf(o2) | ((unsigned)f2bf(o3) << 16);
      *(uint2*)(&Xl[pl * 64 + ((qg ^ (pl & 7)) << 3) + h8 * 4]) = make_uint2(lo, hi);
    }
    __syncthreads();
#pragma unroll
    for (int ks = 0; ks < 2; ks++) {
      const int g = ks * 4 + lg;
      bf16x8 wf[4], xf[4];
#pragma unroll
      for (int i = 0; i < 4; i++) {
        int row = w * 64 + i * 16 + lr;
        wf[i] = *(const bf16x8*)&Wl[row * 64 + ((g ^ (row & 7)) << 3)];
      }
#pragma unroll
      for (int i = 0; i < 4; i++) {
        int row = i * 16 + lr;
        xf[i] = *(const bf16x8*)&Xl[row * 64 + ((g ^ (row & 7)) << 3)];
      }
#pragma unroll
      for (int mi = 0; mi < 4; mi++)
#pragma unroll
        for (int ni = 0; ni < 4; ni++)
          acc[mi][ni] = __builtin_amdgcn_mfma_f32_16x16x32_bf16(
              wf[mi], xf[ni], acc[mi][ni], 0, 0, 0);
    }
    __syncthreads();
  }
  // epilogue: D[o][p] -> bf16 channel-last
#pragma unroll
  for (int mi = 0; mi < 4; mi++)
#pragma unroll
    for (int ni = 0; ni < 4; ni++) {
      int o = w * 64 + mi * 16 + lg * 4;
      int p = pblk + ni * 16 + lr;
      f32x4 a = acc[mi][ni];
      uint2 u;
      u.x = (unsigned)f2bf(a[0]) | ((unsigned)f2bf(a[1]) << 16);
      u.y = (unsigned)f2bf(a[2]) | ((unsigned)f2bf(a[3]) << 16);
      *(uint2*)(Y + (size_t)p * CCH + o) = u;
    }
}

// ---------------------------------------------------------------------------
// Out-projection GEMM (former MODE 1): bf16 CL in -> f32 NCHW out + bias.
// ---------------------------------------------------------------------------
__global__ __launch_bounds__(256)
void gemm_out_m(const u16* __restrict__ Xbuf, const u16* __restrict__ Wbf,
                const float* __restrict__ bias, float* __restrict__ outY) {
  __shared__ u16 Wl[256 * 64];
  __shared__ u16 Xl[64 * 64];
  const int t = threadIdx.x;
  const int w = t >> 6, l = t & 63;
  const int lr = l & 15, lg = l >> 4;
  const int pblk = blockIdx.x * 64;
  const int z = blockIdx.z;
  const u16* Xb = Xbuf + (size_t)z * ((size_t)PP * CCH);

  f32x4 acc[4][4];
#pragma unroll
  for (int mi = 0; mi < 4; mi++)
#pragma unroll
    for (int ni = 0; ni < 4; ni++) acc[mi][ni] = (f32x4){0.f, 0.f, 0.f, 0.f};

  for (int kk = 0; kk < 4; kk++) {
    const int c0 = kk * 64;
#pragma unroll
    for (int i = 0; i < 8; i++) {
      int r0 = (w * 8 + i) * 8;
      int row = r0 + (l >> 3);
      int gs = (l & 7) ^ (row & 7);
      gload16(Wbf + (size_t)row * CCH + c0 + gs * 8, (void*)&Wl[r0 * 64]);
    }
#pragma unroll
    for (int i = 0; i < 2; i++) {
      int r0 = (w * 2 + i) * 8;
      int row = r0 + (l >> 3);
      int gs = (l & 7) ^ (row & 7);
      gload16(Xb + (size_t)(pblk + row) * CCH + c0 + gs * 8, (void*)&Xl[r0 * 64]);
    }
    __syncthreads();
#pragma unroll
    for (int ks = 0; ks < 2; ks++) {
      const int g = ks * 4 + lg;
      bf16x8 wf[4], xf[4];
#pragma unroll
      for (int i = 0; i < 4; i++) {
        int row = w * 64 + i * 16 + lr;
        wf[i] = *(const bf16x8*)&Wl[row * 64 + ((g ^ (row & 7)) << 3)];
      }
#pragma unroll
      for (int i = 0; i < 4; i++) {
        int row = i * 16 + lr;
        xf[i] = *(const bf16x8*)&Xl[row * 64 + ((g ^ (row & 7)) << 3)];
      }
#pragma unroll
      for (int mi = 0; mi < 4; mi++)
#pragma unroll
        for (int ni = 0; ni < 4; ni++)
          acc[mi][ni] = __builtin_amdgcn_mfma_f32_16x16x32_bf16(
              xf[mi], wf[ni], acc[mi][ni], 0, 0, 0);
    }
    __syncthreads();
  }
#pragma unroll
  for (int ni = 0; ni < 4; ni++) {
    int o = w * 64 + ni * 16 + lr;
    float bv = bias[o];
#pragma unroll
    for (int mi = 0; mi < 4; mi++) {
      int p = pblk + mi * 16 + lg * 4;
      f32x4 a = acc[mi][ni];
      float4 st = {a[0] + bv, a[1] + bv, a[2] + bv, a[3] + bv};
      *(float4*)(outY + ((size_t)z * CCH + o) * PP + p) = st;
    }
  }
}

// ---------------------------------------------------------------------------
// Attention, single-barrier: separate bf16 K/V LDS halos staged fully up
// front (all loads in flight), ONE barrier, then scores/PE/softmax/PV with
// no further syncs. Granule swizzle (g + (pix>>1))&3 on 16B slots ->
// conflict-free b128 reads (8 words/bank). Tile 32x4, halo 34x6.
// ---------------------------------------------------------------------------
#define TX 32
#define TY 4
#define HX 34
#define HY 6
#define NHP (HX * HY)    // 204 halo pixels
#define NGR (NHP * 4)    // 816 16B granules per tensor
#define ARND 4

__device__ __forceinline__ void fma8(const uint4 u, const float* qp, float& s) {
  s = fmaf(qp[0], bf2f(u.x & 0xffffu), s);
  s = fmaf(qp[1], bf2f(u.x >> 16), s);
  s = fmaf(qp[2], bf2f(u.y & 0xffffu), s);
  s = fmaf(qp[3], bf2f(u.y >> 16), s);
  s = fmaf(qp[4], bf2f(u.z & 0xffffu), s);
  s = fmaf(qp[5], bf2f(u.z >> 16), s);
  s = fmaf(qp[6], bf2f(u.w & 0xffffu), s);
  s = fmaf(qp[7], bf2f(u.w >> 16), s);
}
__device__ __forceinline__ void acc8(const uint4 u, float gv, float* op) {
  op[0] = fmaf(gv, bf2f(u.x & 0xffffu), op[0]);
  op[1] = fmaf(gv, bf2f(u.x >> 16), op[1]);
  op[2] = fmaf(gv, bf2f(u.y & 0xffffu), op[2]);
  op[3] = fmaf(gv, bf2f(u.y >> 16), op[3]);
  op[4] = fmaf(gv, bf2f(u.z & 0xffffu), op[4]);
  op[5] = fmaf(gv, bf2f(u.z >> 16), op[5]);
  op[6] = fmaf(gv, bf2f(u.w & 0xffffu), op[6]);
  op[7] = fmaf(gv, bf2f(u.w >> 16), op[7]);
}

__global__ __launch_bounds__(256)
void attn_1b(const u16* __restrict__ Kt, const u16* __restrict__ Vt,
             u16* __restrict__ Qt, const float* __restrict__ pe_dw,
             const float* __restrict__ pe_pw) {
  __shared__ __align__(16) u16 kl[NHP * 32];   // 13,056 B
  __shared__ __align__(16) u16 vl[NHP * 32];   // 13,056 B
  __shared__ float coef[81];
  const int t = threadIdx.x;
  if (t < 81) coef[t] = pe_pw[t] * pe_dw[t % 9];

  const int lx = t & 31;
  const int h2 = (t >> 5) & 1;
  const int ly = t >> 6;
  const int x0 = blockIdx.x * TX;
  const int y0 = blockIdx.y * TY;
  const int b = blockIdx.z >> 3;
  const int h = blockIdx.z & 7;
  const size_t nbase = (size_t)b * PP * CCH + h * CH;
  const int p = (y0 + ly) * WW + (x0 + lx);
  const size_t pixhalf = nbase + (size_t)p * CCH + h2 * 16;

  // ---- issue ALL staged loads up front (K granules, V granules, Q) ----
  uint4 kg[ARND], vg[ARND];
#pragma unroll
  for (int r = 0; r < ARND; r++) {
    int s = t + r * 256;
    int pix = s >> 2, g = s & 3;
    int hy = pix / HX, hx = pix - hy * HX;
    int gx = x0 - 1 + hx, gy = y0 - 1 + hy;
    bool ok = (s < NGR) & (gx >= 0) & (gx < WW) & (gy >= 0) & (gy < HH);
    uint4 u = make_uint4(0u, 0u, 0u, 0u);
    if (ok) u = *(const uint4*)(Kt + nbase + (size_t)(gy * WW + gx) * CCH + g * 8);
    kg[r] = u;
  }
#pragma unroll
  for (int r = 0; r < ARND; r++) {
    int s = t + r * 256;
    int pix = s >> 2, g = s & 3;
    int hy = pix / HX, hx = pix - hy * HX;
    int gx = x0 - 1 + hx, gy = y0 - 1 + hy;
    bool ok = (s < NGR) & (gx >= 0) & (gx < WW) & (gy >= 0) & (gy < HH);
    uint4 u = make_uint4(0u, 0u, 0u, 0u);
    if (ok) u = *(const uint4*)(Vt + nbase + (size_t)(gy * WW + gx) * CCH + g * 8);
    vg[r] = u;
  }
  uint4 q0 = *(const uint4*)(Qt + pixhalf);
  uint4 q1 = *(const uint4*)(Qt + pixhalf + 8);

  // ---- LDS writes (swizzled granules), then the ONE barrier ----
#pragma unroll
  for (int r = 0; r < ARND; r++) {
    int s = t + r * 256;
    if (s < NGR) {
      int pix = s >> 2, g = s & 3;
      *(uint4*)(&kl[pix * 32 + (((g + (pix >> 1)) & 3) << 3)]) = kg[r];
    }
  }
#pragma unroll
  for (int r = 0; r < ARND; r++) {
    int s = t + r * 256;
    if (s < NGR) {
      int pix = s >> 2, g = s & 3;
      *(uint4*)(&vl[pix * 32 + (((g + (pix >> 1)) & 3) << 3)]) = vg[r];
    }
  }
  __syncthreads();

  float qh[16];
  qh[0] = bf2f(q0.x & 0xffffu); qh[1] = bf2f(q0.x >> 16);
  qh[2] = bf2f(q0.y & 0xffffu); qh[3] = bf2f(q0.y >> 16);
  qh[4] = bf2f(q0.z & 0xffffu); qh[5] = bf2f(q0.z >> 16);
  qh[6] = bf2f(q0.w & 0xffffu); qh[7] = bf2f(q0.w >> 16);
  qh[8] = bf2f(q1.x & 0xffffu); qh[9] = bf2f(q1.x >> 16);
  qh[10] = bf2f(q1.y & 0xffffu); qh[11] = bf2f(q1.y >> 16);
  qh[12] = bf2f(q1.z & 0xffffu); qh[13] = bf2f(q1.z >> 16);
  qh[14] = bf2f(q1.w & 0xffffu); qh[15] = bf2f(q1.w >> 16);

  // ---- scores: 16-ch half-dot from LDS + cross-half shuffle ----
  float f[9];
#pragma unroll
  for (int kk = 0; kk < 9; kk++) {
    int pix = (ly + kk / 3) * HX + lx + kk % 3;
    int ga = h2 * 2;
    uint4 ka = *(const uint4*)(&kl[pix * 32 + (((ga + (pix >> 1)) & 3) << 3)]);
    uint4 kb = *(const uint4*)(&kl[pix * 32 + (((ga + 1 + (pix >> 1)) & 3) << 3)]);
    float s = 0.f;
    fma8(ka, qh, s);
    fma8(kb, qh + 8, s);
    f[kk] = s + __shfl_xor(s, 32, 64);
  }

  // ---- PE mix + softmax over 9 (duplicated in both halves) ----
  float g[9], m = -1e30f;
#pragma unroll
  for (int k2 = 0; k2 < 9; k2++) {
    float s = 0.f;
#pragma unroll
    for (int kk = 0; kk < 9; kk++) s = fmaf(coef[k2 * 9 + kk], f[kk], s);
    g[k2] = s;
    m = fmaxf(m, s);
  }
  float ssum = 0.f;
#pragma unroll
  for (int k2 = 0; k2 < 9; k2++) {
    g[k2] = __expf(g[k2] - m);
    ssum += g[k2];
  }
  float inv = 1.f / ssum;
#pragma unroll
  for (int k2 = 0; k2 < 9; k2++) g[k2] *= inv;

  // ---- PV: O half = sum_k g[k] * V_half[neighbor k] ----
  float oh[16];
#pragma unroll
  for (int j = 0; j < 16; j++) oh[j] = 0.f;
#pragma unroll
  for (int kk = 0; kk < 9; kk++) {
    int pix = (ly + kk / 3) * HX + lx + kk % 3;
    int ga = h2 * 2;
    uint4 va = *(const uint4*)(&vl[pix * 32 + (((ga + (pix >> 1)) & 3) << 3)]);
    uint4 vb = *(const uint4*)(&vl[pix * 32 + (((ga + 1 + (pix >> 1)) & 3) << 3)]);
    acc8(va, g[kk], oh);
    acc8(vb, g[kk], oh + 8);
  }
  uint4 s0, s1;
  s0.x = (unsigned)f2bf(oh[0]) | ((unsigned)f2bf(oh[1]) << 16);
  s0.y = (unsigned)f2bf(oh[2]) | ((unsigned)f2bf(oh[3]) << 16);
  s0.z = (unsigned)f2bf(oh[4]) | ((unsigned)f2bf(oh[5]) << 16);
  s0.w = (unsigned)f2bf(oh[6]) | ((unsigned)f2bf(oh[7]) << 16);
  s1.x = (unsigned)f2bf(oh[8]) | ((unsigned)f2bf(oh[9]) << 16);
  s1.y = (unsigned)f2bf(oh[10]) | ((unsigned)f2bf(oh[11]) << 16);
  s1.z = (unsigned)f2bf(oh[12]) | ((unsigned)f2bf(oh[13]) << 16);
  s1.w = (unsigned)f2bf(oh[14]) | ((unsigned)f2bf(oh[15]) << 16);
  *(uint4*)(Qt + pixhalf) = s0;
  *(uint4*)(Qt + pixhalf + 8) = s1;
}

// ---------------------------------------------------------------------------
extern "C" void kernel_launch(void* const* d_in, const int* in_sizes, int n_in,
                              void* d_out, int out_size, void* d_ws, size_t ws_size,
                              hipStream_t stream) {
  const float* q     = (const float*)d_in[0];
  const float* k     = (const float*)d_in[1];
  const float* v     = (const float*)d_in[2];
  const float* wq    = (const float*)d_in[3];
  const float* pe_dw = (const float*)d_in[4];
  const float* pe_pw = (const float*)d_in[5];
  const float* wo    = (const float*)d_in[6];
  const float* bo    = (const float*)d_in[7];
  float* out = (float*)d_out;

  const size_t seg = (size_t)BB * PP * CCH;      // elements per [B,P,C] tensor
  u16* Xcl = (u16*)d_ws;                         // 3*seg bf16: q,k,v projections
  u16* Wbf = Xcl + 3 * seg;                      // 131072 bf16: wq | wo

  wcvt<<<128, 256, 0, stream>>>(wq, wo, Wbf);

  // fused convert+transpose+projection: z = which*4 + b
  gemm_qkvf<<<dim3(PP / 64, 1, 12), 256, 0, stream>>>(q, k, v, Wbf, Xcl);

  u16* Qs = Xcl;
  u16* Ks = Xcl + seg;
  u16* Vs = Xcl + 2 * seg;
  attn_1b<<<dim3(WW / TX, HH / TY, BB * 8), 256, 0, stream>>>(Ks, Vs, Qs, pe_dw, pe_pw);

  gemm_out_m<<<dim3(PP / 64, 1, BB), 256, 0, stream>>>(Qs, Wbf + 65536, bo, out);
}